// Round 4
// baseline (221.154 us; speedup 1.0000x reference)
//
#include <hip/hip_runtime.h>

// Sparsemax along last axis, D=32, rows = 1024*4096 = 4,194,304.
//
// Layout: one row per 8-lane group; each lane holds one float4 (4 elements).
// Persistent grid (2048 blocks x 256 thr = 8 WG/CU), grid-stride over 64
// chunks/thread with explicit next-chunk prefetch so a load is always in
// flight while computing (closes the WG-launch/retire memory-pipe gaps of the
// one-chunk-per-thread version).
//
// Michelot = Newton on f(tau) = sum(max(e-tau,0)) - 1:
//   tau += (sum_grp max(e-tau,0) - 1) / count_grp   until count stops changing.
// tau monotone non-decreasing, count >= 1 always. 8-lane group reductions via
// DPP adds (quad_perm xor1, xor2, row_half_mirror) - VALU pipe only, no LDS.
// Division replaced by v_rcp_f32 (C is an exact small integer; <=1 ulp).

typedef float fx4 __attribute__((ext_vector_type(4)));  // native vector: ok for
                                                        // __builtin_nontemporal_*

template <int CTRL>
__device__ __forceinline__ float dpp_movf(float v) {
    return __int_as_float(
        __builtin_amdgcn_update_dpp(0, __float_as_int(v), CTRL, 0xF, 0xF, true));
}
template <int CTRL>
__device__ __forceinline__ int dpp_movi(int v) {
    return __builtin_amdgcn_update_dpp(0, v, CTRL, 0xF, 0xF, true);
}

// Sum over each aligned 8-lane group; result valid in all 8 lanes.
__device__ __forceinline__ float reduce8f(float v) {
    v += dpp_movf<0xB1>(v);   // quad_perm [1,0,3,2] : xor 1
    v += dpp_movf<0x4E>(v);   // quad_perm [2,3,0,1] : xor 2
    v += dpp_movf<0x141>(v);  // row_half_mirror     : combine quads
    return v;
}
__device__ __forceinline__ int reduce8i(int v) {
    v += dpp_movi<0xB1>(v);
    v += dpp_movi<0x4E>(v);
    v += dpp_movi<0x141>(v);
    return v;
}

__device__ __forceinline__ fx4 sparsemax_chunk(fx4 v) {
    float e0 = v.x, e1 = v.y, e2 = v.z, e3 = v.w;

    // Iteration 0: full-set estimate.
    float S = reduce8f(e0 + e1 + e2 + e3);
    float tau = (S - 1.0f) * 0.03125f;
    int Cprev = 32;

#pragma unroll 1
    for (int it = 0; it < 32; ++it) {
        float m0 = fmaxf(e0 - tau, 0.0f);
        float m1 = fmaxf(e1 - tau, 0.0f);
        float m2 = fmaxf(e2 - tau, 0.0f);
        float m3 = fmaxf(e3 - tau, 0.0f);
        float sm = reduce8f((m0 + m1) + (m2 + m3));

        int c = 0;
        c += (e0 > tau) ? 1 : 0;
        c += (e1 > tau) ? 1 : 0;
        c += (e2 > tau) ? 1 : 0;
        c += (e3 > tau) ? 1 : 0;
        int C = reduce8i(c);

        tau += (sm - 1.0f) * __builtin_amdgcn_rcpf((float)C);

        bool done = (C == Cprev);     // support unchanged -> fixed point
        Cprev = C;
        if (__all(done)) break;
    }

    fx4 o;
    o.x = fmaxf(e0 - tau, 0.0f);
    o.y = fmaxf(e1 - tau, 0.0f);
    o.z = fmaxf(e2 - tau, 0.0f);
    o.w = fmaxf(e3 - tau, 0.0f);
    return o;
}

__global__ __launch_bounds__(256) void sparsemax_kernel(const fx4* __restrict__ in4,
                                                        fx4* __restrict__ out4,
                                                        int n4, int niter) {
    const int stride = gridDim.x * blockDim.x;          // in float4 units
    const int tid = blockIdx.x * blockDim.x + threadIdx.x;

    fx4 v = __builtin_nontemporal_load(&in4[tid]);      // prologue load
#pragma unroll 1
    for (int i = 0; i < niter; ++i) {
        const int t = tid + i * stride;
        fx4 cur = v;
        if (i + 1 < niter)                               // prefetch next chunk
            v = __builtin_nontemporal_load(&in4[t + stride]);
        fx4 o = sparsemax_chunk(cur);
        __builtin_nontemporal_store(o, &out4[t]);
    }
    // Tail (never taken for n4 = 2^25, stride = 2^19; kept for generality).
    const int t = tid + niter * stride;
    if (t < n4) {
        fx4 o = sparsemax_chunk(__builtin_nontemporal_load(&in4[t]));
        __builtin_nontemporal_store(o, &out4[t]);
    }
}

extern "C" void kernel_launch(void* const* d_in, const int* in_sizes, int n_in,
                              void* d_out, int out_size, void* d_ws, size_t ws_size,
                              hipStream_t stream) {
    const fx4* in4 = (const fx4*)d_in[0];
    fx4* out4 = (fx4*)d_out;
    int n4 = in_sizes[0] / 4;            // 33,554,432 float4s
    int block = 256;
    int grid = 2048;                     // 8 WG/CU on 256 CUs, persistent
    int stride = grid * block;           // 524,288
    int niter = n4 / stride;             // 64 (exact)
    sparsemax_kernel<<<grid, block, 0, stream>>>(in4, out4, n4, niter);
}

// Round 5
// 186.096 us; speedup vs baseline: 1.1884x; 1.1884x over previous
//
#include <hip/hip_runtime.h>

// Sparsemax along last axis, D=32, rows = 1024*4096 = 4,194,304.
//
// Structure (R2-proven): one-shot grid, one chunk-pair per thread. Each row =
// one aligned 8-lane group; each lane holds one float4. Flat float4 index ==
// thread id -> perfectly coalesced 1-KiB wave loads/stores.
//
// R5 change: 2 chunks/thread from two contiguous streams (t and t+n4/2).
//  - MLP=2: both loads issue at wave start (2 KiB in flight per wave).
//  - ILP=2: two independent Michelot chains interleave in the VALU, hiding
//    the latency-bound DPP reduce chain (~40-60 cyc serial per iteration).
// No nontemporal flags, no persistent loop (both regressed in R4: the wave
// launch churn is the prefetch mechanism for streaming kernels).
//
// Michelot = Newton on f(tau) = sum(max(e-tau,0)) - 1:
//   tau += (sum_grp max(e-tau,0) - 1)/count_grp  until count stops changing.
// tau monotone non-decreasing, count >= 1 always. Group reductions via DPP
// adds (quad_perm xor1, xor2, row_half_mirror) - VALU only, no LDS.

typedef float fx4 __attribute__((ext_vector_type(4)));

template <int CTRL>
__device__ __forceinline__ float dpp_movf(float v) {
    return __int_as_float(
        __builtin_amdgcn_update_dpp(0, __float_as_int(v), CTRL, 0xF, 0xF, true));
}
template <int CTRL>
__device__ __forceinline__ int dpp_movi(int v) {
    return __builtin_amdgcn_update_dpp(0, v, CTRL, 0xF, 0xF, true);
}

// Sum over each aligned 8-lane group; result valid in all 8 lanes.
__device__ __forceinline__ float reduce8f(float v) {
    v += dpp_movf<0xB1>(v);   // quad_perm [1,0,3,2] : xor 1
    v += dpp_movf<0x4E>(v);   // quad_perm [2,3,0,1] : xor 2
    v += dpp_movf<0x141>(v);  // row_half_mirror     : combine quads
    return v;
}
__device__ __forceinline__ int reduce8i(int v) {
    v += dpp_movi<0xB1>(v);
    v += dpp_movi<0x4E>(v);
    v += dpp_movi<0x141>(v);
    return v;
}

__global__ __launch_bounds__(256) void sparsemax_kernel(const fx4* __restrict__ in4,
                                                        fx4* __restrict__ out4,
                                                        int half) {
    const int t = blockIdx.x * blockDim.x + threadIdx.x;
    if (t >= half) return;

    fx4 va = in4[t];           // both loads in flight before any compute
    fx4 vb = in4[t + half];

    float a0 = va.x, a1 = va.y, a2 = va.z, a3 = va.w;
    float b0 = vb.x, b1 = vb.y, b2 = vb.z, b3 = vb.w;

    // Iteration 0: full-set estimates (independent chains interleave).
    float SA = reduce8f((a0 + a1) + (a2 + a3));
    float SB = reduce8f((b0 + b1) + (b2 + b3));
    float tauA = (SA - 1.0f) * 0.03125f;
    float tauB = (SB - 1.0f) * 0.03125f;
    int CAp = 32, CBp = 32;

#pragma unroll 1
    for (int it = 0; it < 32; ++it) {
        float sa = fmaxf(a0 - tauA, 0.0f) + fmaxf(a1 - tauA, 0.0f)
                 + fmaxf(a2 - tauA, 0.0f) + fmaxf(a3 - tauA, 0.0f);
        float sb = fmaxf(b0 - tauB, 0.0f) + fmaxf(b1 - tauB, 0.0f)
                 + fmaxf(b2 - tauB, 0.0f) + fmaxf(b3 - tauB, 0.0f);
        float SmA = reduce8f(sa);
        float SmB = reduce8f(sb);

        int ca = ((a0 > tauA) ? 1 : 0) + ((a1 > tauA) ? 1 : 0)
               + ((a2 > tauA) ? 1 : 0) + ((a3 > tauA) ? 1 : 0);
        int cb = ((b0 > tauB) ? 1 : 0) + ((b1 > tauB) ? 1 : 0)
               + ((b2 > tauB) ? 1 : 0) + ((b3 > tauB) ? 1 : 0);
        int CA = reduce8i(ca);
        int CB = reduce8i(cb);

        tauA += (SmA - 1.0f) * __builtin_amdgcn_rcpf((float)CA);
        tauB += (SmB - 1.0f) * __builtin_amdgcn_rcpf((float)CB);

        bool done = (CA == CAp) & (CB == CBp);  // support unchanged -> fixed
        CAp = CA;                               // point (idempotent updates)
        CBp = CB;
        if (__all(done)) break;
    }

    fx4 oa, ob;
    oa.x = fmaxf(a0 - tauA, 0.0f);
    oa.y = fmaxf(a1 - tauA, 0.0f);
    oa.z = fmaxf(a2 - tauA, 0.0f);
    oa.w = fmaxf(a3 - tauA, 0.0f);
    ob.x = fmaxf(b0 - tauB, 0.0f);
    ob.y = fmaxf(b1 - tauB, 0.0f);
    ob.z = fmaxf(b2 - tauB, 0.0f);
    ob.w = fmaxf(b3 - tauB, 0.0f);
    out4[t] = oa;
    out4[t + half] = ob;
}

extern "C" void kernel_launch(void* const* d_in, const int* in_sizes, int n_in,
                              void* d_out, int out_size, void* d_ws, size_t ws_size,
                              hipStream_t stream) {
    const fx4* in4 = (const fx4*)d_in[0];
    fx4* out4 = (fx4*)d_out;
    int n4 = in_sizes[0] / 4;            // 33,554,432 float4s
    int half = n4 / 2;                   // 16,777,216 (row-group alignment kept:
                                         // half % 8 == 0)
    int block = 256;
    int grid = (half + block - 1) / block;  // 65,536 blocks
    sparsemax_kernel<<<grid, block, 0, stream>>>(in4, out4, half);
}

// Round 6
// 183.188 us; speedup vs baseline: 1.2073x; 1.0159x over previous
//
#include <hip/hip_runtime.h>

// Sparsemax along last axis, D=32, rows = 1024*4096 = 4,194,304.
//
// Structure (R5-proven, 186.1 us): one-shot grid, 2 chunks/thread from two
// contiguous streams (t, t+n4/2). Each row = one aligned 8-lane group; each
// lane holds one float4. Flat float4 index == thread id -> perfectly
// coalesced 1-KiB wave loads/stores. MLP=2 (both loads issue at wave start),
// ILP=2 (two independent Michelot chains interleave in the VALU).
//
// R6 single change (isolated A/B vs R5): non-temporal hints on both streams.
// 1 GiB streamed read-once/write-once per replay = 4x the 256 MiB L3 ->
// cache allocation is pure thrash; nt marks lines streaming (no allocate /
// evict-first), cutting victim-writeback interference between the read and
// write streams. R4 bundled nt with the regressive persistent loop; this
// isolates it.
//
// Michelot = Newton on f(tau) = sum(max(e-tau,0)) - 1:
//   tau += (sum_grp max(e-tau,0) - 1)/count_grp  until count stops changing.
// tau monotone non-decreasing, count >= 1 always. Group reductions via DPP
// adds (quad_perm xor1, xor2, row_half_mirror) - VALU only, no LDS.

typedef float fx4 __attribute__((ext_vector_type(4)));

template <int CTRL>
__device__ __forceinline__ float dpp_movf(float v) {
    return __int_as_float(
        __builtin_amdgcn_update_dpp(0, __float_as_int(v), CTRL, 0xF, 0xF, true));
}
template <int CTRL>
__device__ __forceinline__ int dpp_movi(int v) {
    return __builtin_amdgcn_update_dpp(0, v, CTRL, 0xF, 0xF, true);
}

// Sum over each aligned 8-lane group; result valid in all 8 lanes.
__device__ __forceinline__ float reduce8f(float v) {
    v += dpp_movf<0xB1>(v);   // quad_perm [1,0,3,2] : xor 1
    v += dpp_movf<0x4E>(v);   // quad_perm [2,3,0,1] : xor 2
    v += dpp_movf<0x141>(v);  // row_half_mirror     : combine quads
    return v;
}
__device__ __forceinline__ int reduce8i(int v) {
    v += dpp_movi<0xB1>(v);
    v += dpp_movi<0x4E>(v);
    v += dpp_movi<0x141>(v);
    return v;
}

__global__ __launch_bounds__(256) void sparsemax_kernel(const fx4* __restrict__ in4,
                                                        fx4* __restrict__ out4,
                                                        int half) {
    const int t = blockIdx.x * blockDim.x + threadIdx.x;
    if (t >= half) return;

    fx4 va = __builtin_nontemporal_load(&in4[t]);        // both loads in
    fx4 vb = __builtin_nontemporal_load(&in4[t + half]); // flight up front

    float a0 = va.x, a1 = va.y, a2 = va.z, a3 = va.w;
    float b0 = vb.x, b1 = vb.y, b2 = vb.z, b3 = vb.w;

    // Iteration 0: full-set estimates (independent chains interleave).
    float SA = reduce8f((a0 + a1) + (a2 + a3));
    float SB = reduce8f((b0 + b1) + (b2 + b3));
    float tauA = (SA - 1.0f) * 0.03125f;
    float tauB = (SB - 1.0f) * 0.03125f;
    int CAp = 32, CBp = 32;

#pragma unroll 1
    for (int it = 0; it < 32; ++it) {
        float sa = fmaxf(a0 - tauA, 0.0f) + fmaxf(a1 - tauA, 0.0f)
                 + fmaxf(a2 - tauA, 0.0f) + fmaxf(a3 - tauA, 0.0f);
        float sb = fmaxf(b0 - tauB, 0.0f) + fmaxf(b1 - tauB, 0.0f)
                 + fmaxf(b2 - tauB, 0.0f) + fmaxf(b3 - tauB, 0.0f);
        float SmA = reduce8f(sa);
        float SmB = reduce8f(sb);

        int ca = ((a0 > tauA) ? 1 : 0) + ((a1 > tauA) ? 1 : 0)
               + ((a2 > tauA) ? 1 : 0) + ((a3 > tauA) ? 1 : 0);
        int cb = ((b0 > tauB) ? 1 : 0) + ((b1 > tauB) ? 1 : 0)
               + ((b2 > tauB) ? 1 : 0) + ((b3 > tauB) ? 1 : 0);
        int CA = reduce8i(ca);
        int CB = reduce8i(cb);

        tauA += (SmA - 1.0f) * __builtin_amdgcn_rcpf((float)CA);
        tauB += (SmB - 1.0f) * __builtin_amdgcn_rcpf((float)CB);

        bool done = (CA == CAp) & (CB == CBp);  // support unchanged -> fixed
        CAp = CA;                               // point (idempotent updates)
        CBp = CB;
        if (__all(done)) break;
    }

    fx4 oa, ob;
    oa.x = fmaxf(a0 - tauA, 0.0f);
    oa.y = fmaxf(a1 - tauA, 0.0f);
    oa.z = fmaxf(a2 - tauA, 0.0f);
    oa.w = fmaxf(a3 - tauA, 0.0f);
    ob.x = fmaxf(b0 - tauB, 0.0f);
    ob.y = fmaxf(b1 - tauB, 0.0f);
    ob.z = fmaxf(b2 - tauB, 0.0f);
    ob.w = fmaxf(b3 - tauB, 0.0f);
    __builtin_nontemporal_store(oa, &out4[t]);
    __builtin_nontemporal_store(ob, &out4[t + half]);
}

extern "C" void kernel_launch(void* const* d_in, const int* in_sizes, int n_in,
                              void* d_out, int out_size, void* d_ws, size_t ws_size,
                              hipStream_t stream) {
    const fx4* in4 = (const fx4*)d_in[0];
    fx4* out4 = (fx4*)d_out;
    int n4 = in_sizes[0] / 4;            // 33,554,432 float4s
    int half = n4 / 2;                   // 16,777,216 (row-group alignment kept:
                                         // half % 8 == 0)
    int block = 256;
    int grid = (half + block - 1) / block;  // 65,536 blocks
    sparsemax_kernel<<<grid, block, 0, stream>>>(in4, out4, half);
}